// Round 14
// baseline (76.840 us; speedup 1.0000x reference)
//
#include <hip/hip_runtime.h>

// DILATE loss: 0.5*soft-DTW(value) + 0.5*<softDTW-grad, Omega>.
// B=64, T=128, C=4 -> M=256 independent sequences, N=128, gamma=0.01.
//
// Fused forward pass carrying (R', Rdot): R' = -K2*R (log2-scaled), Rdot =
// JVP of soft-DTW value in direction Omega == sum(E*Omega).
//
// Structure (R13, verified absmax 0.0): 128 blocks x 256 threads; block =
// 2 sequences x (producer wave: rows 1..64, consumer wave: rows 65..128).
// Row-64 boundary passes through LDS float2 Bb[]; producer release-publishes
// progress every KCH=8 steps, consumer acquire-gates per chunk. DAG critical
// path = 255 diagonals; measured 224 cyc/step vs 194 for the bare step.
//
// R14 changes: (1) s_sleep(1) in all consumer spin loops — a hot spin issues
// ds_reads every ~6 cyc on the SAME CU whose LDS pipe the producer needs
// (o-prefetch + Bb write each step); during the ~64-step startup gate this
// contends directly with producer progress. (2) producer unroll 8 — publish
// period is 8, so the ((d-1)&7)==0 check constant-folds per unrolled body.

#define TN 128
#define BATCH 64
#define CH 4
#define KCH 8    // pipeline chunk (publish/wait granularity)

__device__ __forceinline__ float fast_exp2(float x) { return __builtin_amdgcn_exp2f(x); }
__device__ __forceinline__ float fast_log2(float x) { return __builtin_amdgcn_logf(x); }
__device__ __forceinline__ float fast_rcp(float x)  { return __builtin_amdgcn_rcpf(x); }

// lane i <- lane i-1, lane 0 <- old(fill)   (DPP wave_shr:1) — HW-verified R4-R13
__device__ __forceinline__ float dpp_shr1(float x, float fill) {
  union { float f; int i; } o, s, r;
  o.f = fill; s.f = x;
  r.i = __builtin_amdgcn_update_dpp(o.i, s.i, 0x138, 0xF, 0xF, false);
  return r.f;
}

__global__ __launch_bounds__(256)
void dilate_softdtw_kernel(const float* __restrict__ outputs,
                           const float* __restrict__ targets,
                           float* __restrict__ out) {
  // per-sequence padded o: oc[k]=o[k] for k in [0,128); pads hold O_PAD.
  __shared__ float obuf[2][384];
  // per-sequence row-64 boundary: Bb[d-1] = {R'[64][j], Rdot[64][j]}, j=d-64.
  // Producer writes 1..191; 192..255 prefilled with wall (kills the clamp).
  __shared__ float2 Bb[2][256];
  __shared__ int prog[2];   // highest d the producer has completed

  const float WALLP = -4.328085e6f;  // -K2*30000: boundary wall, scaled units
  const float O_PAD = 15.0f;         // sentinel: (t-15)^2 ~ 100..400 per OOB step
  const float K2    = 144.2695040888963f;     // (1/gamma)*log2(e)

  const int tid  = threadIdx.x;
  const int wid  = tid >> 6;
  const int lane = tid & 63;
  const int seq  = wid & 1;       // which of the block's two sequences
  const int half = wid >> 1;      // 0: rows 1..64 (producer), 1: rows 65..128 (consumer)

  const int m = blockIdx.x * 2 + seq, b = m >> 2, c = m & 3;
  const float* tb = targets + (size_t)b*(TN*CH) + c;
  const float* ob = outputs + (size_t)b*(TN*CH) + c;

  // staging: the seq's two waves (128 threads) fill obuf[seq].
  const int lid = half*64 + lane;   // 0..127 within the pair
  #pragma unroll
  for (int s = 0; s < 3; ++s) {
    const int idx = lid + 128*s;
    const int k = idx - 126;
    obuf[seq][idx] = ((unsigned)k <= 127u) ? ob[k*CH] : O_PAD;
  }
  if (half == 1) Bb[seq][192 + lane] = make_float2(WALLP, 0.f);  // wall tail
  const float t0 = tb[(half*64 + lane)*CH];   // t[row], row = half*64+lane+1
  if (lid == 0) prog[seq] = 0;
  __syncthreads();

  const float* oc = obuf[seq] + 126;
  int* pp = &prog[seq];
  const float2* BbS = Bb[seq];

  if (half == 0) {
    // ========== producer: rows 1..64 (i = 1+lane), d = 2..192 ==========
    float p1  = WALLP;                          // R'[i][j-1] (left)
    float up2 = (lane == 0) ? 0.0f : WALLP;     // diag pred; lane0 d=2: R'[0][0]=0
    float dp1 = 0.f, dup2 = 0.f;
    float fd  = (float)(2*lane);                // i - j at d=2
    float o0  = oc[-lane];                      // o[j0-1] at d=2

    #pragma unroll 8
    for (int d = 2; d <= 192; ++d) {
      const int j0 = d - 1 - lane;              // j = d - i
      const float o_nxt = oc[j0];
      float up1  = dpp_shr1(p1, WALLP);         // R'[i-1][j]   (row 0 -> wall)
      float dup1 = dpp_shr1(dp1, 0.f);          // Rdot[i-1][j]

      float mn = fmaxf(up2, fmaxf(up1, p1));
      float a = up2 - mn, bq = up1 - mn, cc = p1 - mn;
      float ea = fast_exp2(a);
      float eb = fast_exp2(bq);
      float ec = fast_exp2(cc);
      float sum = (ea + eb) + ec;
      float rs = fast_rcp(sum);
      float l  = fast_log2(sum);
      float df = t0 - o0;
      float q  = df*df;
      float jv = __builtin_fmaf(ea, dup2, __builtin_fmaf(eb, dup1, ec*dp1));
      float w  = fd*fd;
      float cv = __builtin_fmaf(-K2, q, mn + l);
      float dv = __builtin_fmaf(rs, jv, w);

      if (lane == 63) {
        Bb[seq][d - 1] = make_float2(cv, dv);   // boundary cell (64, d-64)
        if (((d - 1) & (KCH - 1)) == 0)         // constant-folds under unroll 8
          __hip_atomic_store(pp, d, __ATOMIC_RELEASE, __HIP_MEMORY_SCOPE_WORKGROUP);
      }

      up2 = up1; p1 = cv; dup2 = dup1; dp1 = dv;
      o0 = o_nxt; fd -= 1.0f;
    }
    if (lane == 63)
      __hip_atomic_store(pp, 1000, __ATOMIC_RELEASE, __HIP_MEMORY_SCOPE_WORKGROUP);
  } else {
    // ========== consumer: rows 65..128 (i = 65+lane), d = 66..256 ==========
    float p1  = WALLP, up2 = WALLP;    // lane0 @d=66 diag pred = R'[64][0] (wall)
    float dp1 = 0.f, dup2 = 0.f;
    float fd  = (float)(64 + 2*lane);  // i - j at d=66
    float o0  = oc[-lane];             // o[j0-1] at d=66

    // one consumer macro-step
    auto cstep = [&](int d, float2& bc) {
      const int j0 = d - 65 - lane;
      const float o_nxt = oc[j0];
      const float2 bn = BbS[d - 1];      // prefetch next iter's boundary (no clamp)
      float up1  = dpp_shr1(p1, bc.x);   // lane 0 <- R'[64][j0]
      float dup1 = dpp_shr1(dp1, bc.y);  // lane 0 <- Rdot[64][j0]

      float mn = fmaxf(up2, fmaxf(up1, p1));
      float a = up2 - mn, bq = up1 - mn, cc = p1 - mn;
      float ea = fast_exp2(a);
      float eb = fast_exp2(bq);
      float ec = fast_exp2(cc);
      float sum = (ea + eb) + ec;
      float rs = fast_rcp(sum);
      float l  = fast_log2(sum);
      float df = t0 - o0;
      float q  = df*df;
      float jv = __builtin_fmaf(ea, dup2, __builtin_fmaf(eb, dup1, ec*dp1));
      float w  = fd*fd;
      float cv = __builtin_fmaf(-K2, q, mn + l);
      float dv = __builtin_fmaf(rs, jv, w);

      up2 = up1; p1 = cv; dup2 = dup1; dp1 = dv;
      o0 = o_nxt; fd -= 1.0f; bc = bn;
    };

    // phase 1: gated chunks d0 = 66, 74, ..., 178 (targets 73..185, all published).
    // s_sleep(1) (~64 cyc nap) keeps the spin off the CU's LDS pipe, which the
    // producer needs every step (o-prefetch read + Bb write).
    while (__hip_atomic_load(pp, __ATOMIC_ACQUIRE, __HIP_MEMORY_SCOPE_WORKGROUP) < 73)
      __builtin_amdgcn_s_sleep(1);
    float2 bc = BbS[64];                        // boundary Bb[d-2] for d=66
    for (int d0 = 66; d0 <= 178; d0 += KCH) {
      const int target = d0 + KCH - 1;
      while (__hip_atomic_load(pp, __ATOMIC_ACQUIRE, __HIP_MEMORY_SCOPE_WORKGROUP) < target)
        __builtin_amdgcn_s_sleep(1);
      #pragma unroll
      for (int k = 0; k < KCH; ++k) cstep(d0 + k, bc);
    }
    // phase 2: wait for producer completion, then branch-free tail d=186..256
    while (__hip_atomic_load(pp, __ATOMIC_ACQUIRE, __HIP_MEMORY_SCOPE_WORKGROUP) < 1000)
      __builtin_amdgcn_s_sleep(1);
    #pragma unroll 4
    for (int d = 186; d <= 256; ++d) cstep(d, bc);

    // lane 63: cell (128,128). R = -gamma*ln2 * R', Rdot = sum(E*Omega).
    if (lane == 63) {
      // 0.5*R/B + 0.5*Rdot/(B*T*T);  0.5*(gamma*ln2)/64 = 5.4152123e-5
      const float partial = __builtin_fmaf(p1, -5.415212348e-5f,
                                           dp1 * 4.76837158203125e-7f);
      atomicAdd(out, partial);
    }
  }
}

extern "C" void kernel_launch(void* const* d_in, const int* in_sizes, int n_in,
                              void* d_out, int out_size, void* d_ws, size_t ws_size,
                              hipStream_t stream) {
  const float* outputs = (const float*)d_in[0];   // [64,128,4]
  const float* targets = (const float*)d_in[1];   // [64,128,4]
  float* out = (float*)d_out;                     // scalar fp32
  (void)in_sizes; (void)n_in; (void)out_size; (void)d_ws; (void)ws_size;

  // d_out is poisoned to 0xAA before every timed launch — zero it ourselves.
  (void)hipMemsetAsync(out, 0, sizeof(float), stream);
  // 128 blocks x 256 threads: 2 sequences/block, each a 2-wave pipeline.
  dilate_softdtw_kernel<<<dim3(128), dim3(256), 0, stream>>>(outputs, targets, out);
}

// Round 15
// 76.705 us; speedup vs baseline: 1.0018x; 1.0018x over previous
//
#include <hip/hip_runtime.h>

// DILATE loss: 0.5*soft-DTW(value) + 0.5*<softDTW-grad, Omega>.
// B=64, T=128, C=4 -> M=256 independent sequences, N=128, gamma=0.01.
//
// FINAL (= R13, best: bench 76.37 us, kernel ~23.9 us, absmax 0.0).
// Fused single forward pass carrying (R', Rdot): R' = -K2*R (log2-scaled),
// Rdot = JVP of the soft-DTW value in direction Omega == sum(E*Omega) —
// eliminates the reverse/backward E-recursion entirely.
//
// Structure: 128 blocks x 256 threads = 2 sequences/block, each a 2-wave
// wavefront pipeline: producer wave = rows 1..64 (d=2..192), consumer wave =
// rows 65..128 (d=66..256), running concurrently on different SIMDs. The
// row-64 boundary passes through LDS float2 Bb[] (producer writes Bb[d-1];
// consumer injects it as lane 0's DPP old-fill). Producer release-publishes
// progress every KCH=8 steps and NEVER waits (deadlock-free); consumer
// acquire-gates per chunk. Critical path = 191 producer + 64 tail = 255
// steps ~ the DAG's floor; measured ~219 cyc/step (5 transcendentals/cell,
// trans-issue + dependency-chain bound).
//
// Verified-closed levers: issue-count trim (R7: neutral, stall-bound),
// LDS-free register pipelines (R9: DPP on chain costs more), SIMD packing
// (R8: k seqs/issue-stream loses), deeper splits (R11/R12: path conserved),
// spin-throttle (R14: regression under profiling, spin was never contending).

#define TN 128
#define BATCH 64
#define CH 4
#define KCH 8    // pipeline chunk (publish/wait granularity)

__device__ __forceinline__ float fast_exp2(float x) { return __builtin_amdgcn_exp2f(x); }
__device__ __forceinline__ float fast_log2(float x) { return __builtin_amdgcn_logf(x); }
__device__ __forceinline__ float fast_rcp(float x)  { return __builtin_amdgcn_rcpf(x); }

// lane i <- lane i-1, lane 0 <- old(fill)   (DPP wave_shr:1) — HW-verified R4-R14
__device__ __forceinline__ float dpp_shr1(float x, float fill) {
  union { float f; int i; } o, s, r;
  o.f = fill; s.f = x;
  r.i = __builtin_amdgcn_update_dpp(o.i, s.i, 0x138, 0xF, 0xF, false);
  return r.f;
}

__global__ __launch_bounds__(256)
void dilate_softdtw_kernel(const float* __restrict__ outputs,
                           const float* __restrict__ targets,
                           float* __restrict__ out) {
  // per-sequence padded o: oc[k]=o[k] for k in [0,128); pads hold O_PAD.
  __shared__ float obuf[2][384];
  // per-sequence row-64 boundary: Bb[d-1] = {R'[64][j], Rdot[64][j]}, j=d-64.
  // Producer writes 1..191; 192..255 prefilled with wall (kills the clamp).
  __shared__ float2 Bb[2][256];
  __shared__ int prog[2];   // highest d the producer has completed

  const float WALLP = -4.328085e6f;  // -K2*30000: boundary wall, scaled units
  const float O_PAD = 15.0f;         // sentinel: (t-15)^2 ~ 100..400 per OOB step
  const float K2    = 144.2695040888963f;     // (1/gamma)*log2(e)

  const int tid  = threadIdx.x;
  const int wid  = tid >> 6;
  const int lane = tid & 63;
  const int seq  = wid & 1;       // which of the block's two sequences
  const int half = wid >> 1;      // 0: rows 1..64 (producer), 1: rows 65..128 (consumer)

  const int m = blockIdx.x * 2 + seq, b = m >> 2, c = m & 3;
  const float* tb = targets + (size_t)b*(TN*CH) + c;
  const float* ob = outputs + (size_t)b*(TN*CH) + c;

  // staging: the seq's two waves (128 threads) fill obuf[seq].
  const int lid = half*64 + lane;   // 0..127 within the pair
  #pragma unroll
  for (int s = 0; s < 3; ++s) {
    const int idx = lid + 128*s;
    const int k = idx - 126;
    obuf[seq][idx] = ((unsigned)k <= 127u) ? ob[k*CH] : O_PAD;
  }
  if (half == 1) Bb[seq][192 + lane] = make_float2(WALLP, 0.f);  // wall tail
  const float t0 = tb[(half*64 + lane)*CH];   // t[row], row = half*64+lane+1
  if (lid == 0) prog[seq] = 0;
  __syncthreads();

  const float* oc = obuf[seq] + 126;
  int* pp = &prog[seq];

  if (half == 0) {
    // ========== producer: rows 1..64 (i = 1+lane), d = 2..192 ==========
    float p1  = WALLP;                          // R'[i][j-1] (left)
    float up2 = (lane == 0) ? 0.0f : WALLP;     // diag pred; lane0 d=2: R'[0][0]=0
    float dp1 = 0.f, dup2 = 0.f;
    float fd  = (float)(2*lane);                // i - j at d=2
    float o0  = oc[-lane];                      // o[j0-1] at d=2

    #pragma unroll 4
    for (int d = 2; d <= 192; ++d) {
      const int j0 = d - 1 - lane;              // j = d - i
      const float o_nxt = oc[j0];
      float up1  = dpp_shr1(p1, WALLP);         // R'[i-1][j]   (row 0 -> wall)
      float dup1 = dpp_shr1(dp1, 0.f);          // Rdot[i-1][j]

      float mn = fmaxf(up2, fmaxf(up1, p1));
      float a = up2 - mn, bq = up1 - mn, cc = p1 - mn;
      float ea = fast_exp2(a);
      float eb = fast_exp2(bq);
      float ec = fast_exp2(cc);
      float sum = (ea + eb) + ec;
      float rs = fast_rcp(sum);
      float l  = fast_log2(sum);
      float df = t0 - o0;
      float q  = df*df;
      float jv = __builtin_fmaf(ea, dup2, __builtin_fmaf(eb, dup1, ec*dp1));
      float w  = fd*fd;
      float cv = __builtin_fmaf(-K2, q, mn + l);
      float dv = __builtin_fmaf(rs, jv, w);

      if (lane == 63) Bb[seq][d - 1] = make_float2(cv, dv);  // cell (64, d-64)
      if (((d - 1) & (KCH - 1)) == 0) {                      // d = 9,17,...,185
        if (lane == 63)
          __hip_atomic_store(pp, d, __ATOMIC_RELEASE, __HIP_MEMORY_SCOPE_WORKGROUP);
      }

      up2 = up1; p1 = cv; dup2 = dup1; dp1 = dv;
      o0 = o_nxt; fd -= 1.0f;
    }
    if (lane == 63)
      __hip_atomic_store(pp, 1000, __ATOMIC_RELEASE, __HIP_MEMORY_SCOPE_WORKGROUP);
  } else {
    // ========== consumer: rows 65..128 (i = 65+lane), d = 66..256 ==========
    float p1  = WALLP, up2 = WALLP;    // lane0 @d=66 diag pred = R'[64][0] (wall)
    float dp1 = 0.f, dup2 = 0.f;
    float fd  = (float)(64 + 2*lane);  // i - j at d=66
    float o0  = oc[-lane];             // o[j0-1] at d=66

    // one consumer macro-step
    auto cstep = [&](int d, float2& bc) {
      const int j0 = d - 65 - lane;
      const float o_nxt = oc[j0];
      const float2 bn = Bb[seq][d - 1];  // prefetch next iter's boundary (no clamp)
      float up1  = dpp_shr1(p1, bc.x);   // lane 0 <- R'[64][j0]
      float dup1 = dpp_shr1(dp1, bc.y);  // lane 0 <- Rdot[64][j0]

      float mn = fmaxf(up2, fmaxf(up1, p1));
      float a = up2 - mn, bq = up1 - mn, cc = p1 - mn;
      float ea = fast_exp2(a);
      float eb = fast_exp2(bq);
      float ec = fast_exp2(cc);
      float sum = (ea + eb) + ec;
      float rs = fast_rcp(sum);
      float l  = fast_log2(sum);
      float df = t0 - o0;
      float q  = df*df;
      float jv = __builtin_fmaf(ea, dup2, __builtin_fmaf(eb, dup1, ec*dp1));
      float w  = fd*fd;
      float cv = __builtin_fmaf(-K2, q, mn + l);
      float dv = __builtin_fmaf(rs, jv, w);

      up2 = up1; p1 = cv; dup2 = dup1; dp1 = dv;
      o0 = o_nxt; fd -= 1.0f; bc = bn;
    };

    // phase 1: gated chunks d0 = 66, 74, ..., 178 (targets 73..185, all published)
    while (__hip_atomic_load(pp, __ATOMIC_ACQUIRE, __HIP_MEMORY_SCOPE_WORKGROUP) < 73) {}
    float2 bc = Bb[seq][64];                    // boundary Bb[d-2] for d=66
    for (int d0 = 66; d0 <= 178; d0 += KCH) {
      const int target = d0 + KCH - 1;
      while (__hip_atomic_load(pp, __ATOMIC_ACQUIRE, __HIP_MEMORY_SCOPE_WORKGROUP) < target) {}
      #pragma unroll
      for (int k = 0; k < KCH; ++k) cstep(d0 + k, bc);
    }
    // phase 2: wait for producer completion, then branch-free tail d=186..256
    while (__hip_atomic_load(pp, __ATOMIC_ACQUIRE, __HIP_MEMORY_SCOPE_WORKGROUP) < 1000) {}
    #pragma unroll 4
    for (int d = 186; d <= 256; ++d) cstep(d, bc);

    // lane 63: cell (128,128). R = -gamma*ln2 * R', Rdot = sum(E*Omega).
    if (lane == 63) {
      // 0.5*R/B + 0.5*Rdot/(B*T*T);  0.5*(gamma*ln2)/64 = 5.4152123e-5
      const float partial = __builtin_fmaf(p1, -5.415212348e-5f,
                                           dp1 * 4.76837158203125e-7f);
      atomicAdd(out, partial);
    }
  }
}

extern "C" void kernel_launch(void* const* d_in, const int* in_sizes, int n_in,
                              void* d_out, int out_size, void* d_ws, size_t ws_size,
                              hipStream_t stream) {
  const float* outputs = (const float*)d_in[0];   // [64,128,4]
  const float* targets = (const float*)d_in[1];   // [64,128,4]
  float* out = (float*)d_out;                     // scalar fp32
  (void)in_sizes; (void)n_in; (void)out_size; (void)d_ws; (void)ws_size;

  // d_out is poisoned to 0xAA before every timed launch — zero it ourselves.
  (void)hipMemsetAsync(out, 0, sizeof(float), stream);
  // 128 blocks x 256 threads: 2 sequences/block, each a 2-wave pipeline.
  dilate_softdtw_kernel<<<dim3(128), dim3(256), 0, stream>>>(outputs, targets, out);
}